// Round 1
// baseline (138.243 us; speedup 1.0000x reference)
//
#include <hip/hip_runtime.h>

// CombinedLoss: 0.7 * class-weighted Dice + 0.3 * Sobel-boundary BCE
// Shapes: logits/targets [B=8, C=4, H=512, W=512] fp32; class_weights [4]; out scalar fp32.
//
// Key simplification: both boundary maps are binary, so BCE with -100 log clamp
// reduces to 100 * mean(pred_b != targ_b). Sobel mag > 0.5  <=>  mag^2 > 0.25.

#define B_ 8
#define C_ 4
#define H_ 512
#define W_ 512
#define NIMG (B_ * C_)                    // 32
#define NPIX ((long long)NIMG * H_ * W_)  // 8388608
#define TH 8                              // rows per block
#define NTHREADS 256

// acc layout in d_ws (floats): [0..31] inter, [32..63] sum_p, [64..95] sum_t, [96] mismatch
__global__ void zero_acc_kernel(float* acc) {
    int i = threadIdx.x;
    if (i < 128) acc[i] = 0.0f;
}

__launch_bounds__(NTHREADS)
__global__ void fused_loss_kernel(const float* __restrict__ logits,
                                  const float* __restrict__ targets,
                                  float* __restrict__ acc) {
    const int bc = blockIdx.y;          // image index b*C + c
    const int y0 = blockIdx.x * TH;     // first output row of this tile
    const float* lg = logits  + (size_t)bc * (H_ * W_);
    const float* tg = targets + (size_t)bc * (H_ * W_);

    __shared__ float sp[TH + 2][W_ + 2];  // sigmoid(logits) tile with halo
    __shared__ float st[TH + 2][W_ + 2];  // targets tile with halo

    const int tid = threadIdx.x;

    // Stage (TH+2) x (W+2) with zero halo (SAME padding)
    const int TOT = (TH + 2) * (W_ + 2);  // 5140
    for (int idx = tid; idx < TOT; idx += NTHREADS) {
        int r  = idx / (W_ + 2);
        int cx = idx - r * (W_ + 2);
        int gy = y0 - 1 + r;
        int gx = cx - 1;
        float pv = 0.0f, tv = 0.0f;
        if (gy >= 0 && gy < H_ && gx >= 0 && gx < W_) {
            float x = lg[gy * W_ + gx];
            pv = 1.0f / (1.0f + __expf(-x));
            tv = tg[gy * W_ + gx];
        }
        sp[r][cx] = pv;
        st[r][cx] = tv;
    }
    __syncthreads();

    float l_inter = 0.0f, l_p = 0.0f, l_t = 0.0f, l_m = 0.0f;

    // Each thread handles TH*W/256 = 16 pixels, stride-256 for conflict-free LDS
    #pragma unroll
    for (int k = 0; k < (TH * W_) / NTHREADS; ++k) {
        int pidx = tid + k * NTHREADS;
        int ry = pidx >> 9;        // / W_
        int rx = pidx & (W_ - 1);  // % W_
        int r = ry + 1, c = rx + 1;

        float pc = sp[r][c];
        float tc = st[r][c];
        l_inter += pc * tc;
        l_p += pc;
        l_t += tc;

        // Sobel (cross-correlation, zero padding) on probs
        float pa = sp[r-1][c-1], pb2 = sp[r-1][c], pcc = sp[r-1][c+1];
        float pd = sp[r  ][c-1],                   pf  = sp[r  ][c+1];
        float pg = sp[r+1][c-1], ph = sp[r+1][c],  pi  = sp[r+1][c+1];
        float gxp = (pcc - pa) + 2.0f * (pf - pd) + (pi - pg);
        float gyp = (pg - pa) + 2.0f * (ph - pb2) + (pi - pcc);
        int pbnd = (gxp * gxp + gyp * gyp) > 0.25f;

        // Sobel on targets (exact: integer arithmetic in fp32)
        float ta = st[r-1][c-1], tb2 = st[r-1][c], tcc = st[r-1][c+1];
        float td = st[r  ][c-1],                   tf  = st[r  ][c+1];
        float tg2 = st[r+1][c-1], th2 = st[r+1][c], ti = st[r+1][c+1];
        float gxt = (tcc - ta) + 2.0f * (tf - td) + (ti - tg2);
        float gyt = (tg2 - ta) + 2.0f * (th2 - tb2) + (ti - tcc);
        int tbnd = (gxt * gxt + gyt * gyt) > 0.25f;

        l_m += (pbnd != tbnd) ? 1.0f : 0.0f;
    }

    // Wave (64-lane) shuffle reduction
    #pragma unroll
    for (int off = 32; off > 0; off >>= 1) {
        l_inter += __shfl_down(l_inter, off, 64);
        l_p     += __shfl_down(l_p,     off, 64);
        l_t     += __shfl_down(l_t,     off, 64);
        l_m     += __shfl_down(l_m,     off, 64);
    }

    __shared__ float red[4][4];
    int wid = tid >> 6, lane = tid & 63;
    if (lane == 0) {
        red[wid][0] = l_inter; red[wid][1] = l_p;
        red[wid][2] = l_t;     red[wid][3] = l_m;
    }
    __syncthreads();
    if (tid == 0) {
        float s0 = 0.f, s1 = 0.f, s2 = 0.f, s3 = 0.f;
        #pragma unroll
        for (int w = 0; w < 4; ++w) {
            s0 += red[w][0]; s1 += red[w][1]; s2 += red[w][2]; s3 += red[w][3];
        }
        atomicAdd(&acc[bc],      s0);
        atomicAdd(&acc[32 + bc], s1);
        atomicAdd(&acc[64 + bc], s2);
        atomicAdd(&acc[96],      s3);  // exact integers up to 2^24 > 8.4M
    }
}

__global__ void finalize_kernel(const float* __restrict__ acc,
                                const float* __restrict__ cw,
                                float* __restrict__ out) {
    if (threadIdx.x == 0) {
        float wsum = 0.0f, dl = 0.0f;
        for (int c = 0; c < C_; ++c) {
            float mean_dice = 0.0f;
            for (int b = 0; b < B_; ++b) {
                int bc = b * C_ + c;
                float inter = acc[bc];
                float sp    = acc[32 + bc];
                float st    = acc[64 + bc];
                mean_dice += (2.0f * inter + 1.0f) / (sp + st + 1.0f);
            }
            mean_dice *= (1.0f / B_);
            dl   += cw[c] * (1.0f - mean_dice);
            wsum += cw[c];
        }
        dl /= wsum;
        float bl = 100.0f * acc[96] / (float)NPIX;
        out[0] = 0.7f * dl + 0.3f * bl;
    }
}

extern "C" void kernel_launch(void* const* d_in, const int* in_sizes, int n_in,
                              void* d_out, int out_size, void* d_ws, size_t ws_size,
                              hipStream_t stream) {
    const float* logits  = (const float*)d_in[0];
    const float* targets = (const float*)d_in[1];
    const float* cw      = (const float*)d_in[2];
    float* out = (float*)d_out;
    float* acc = (float*)d_ws;  // 97 floats used

    zero_acc_kernel<<<1, 128, 0, stream>>>(acc);

    dim3 grid(H_ / TH, NIMG);  // (64, 32) = 2048 blocks
    fused_loss_kernel<<<grid, NTHREADS, 0, stream>>>(logits, targets, acc);

    finalize_kernel<<<1, 64, 0, stream>>>(acc, cw, out);
}

// Round 2
// 108.930 us; speedup vs baseline: 1.2691x; 1.2691x over previous
//
#include <hip/hip_runtime.h>

// CombinedLoss = 0.7 * class-weighted Dice + 0.3 * Sobel-boundary BCE
// [B=8,C=4,H=512,W=512] fp32. Boundary BCE on binary maps == 100 * mismatch-rate.
// Targets are binary {0,1}: target Sobel done in exact integer SWAR on packed bytes;
// boundary <=> gx!=0 || gy!=0. Probs Sobel via separable column sums (vt=1,2,1; vs=bot-top).

#define B_ 8
#define C_ 4
#define H_ 512
#define W_ 512
#define NIMG 32
#define NPIXF 8388608.0f
#define TH 8
#define NT 256
#define NROW (TH + 2)
#define PSTR 524   // prob row stride (floats); 524 mod 32 = 12 -> uniform bank spread for b128
#define TSTR 544   // target row stride (bytes); 136 dwords, mod 32 = 8 -> uniform spread

__launch_bounds__(NT, 4)
__global__ void fused_loss_kernel(const float* __restrict__ logits,
                                  const float* __restrict__ targets,
                                  float4* __restrict__ part) {
    const int bc = blockIdx.y;
    const int y0 = blockIdx.x * TH;
    const float4* lg4 = (const float4*)(logits  + (size_t)bc * (H_ * W_));
    const float4* tg4 = (const float4*)(targets + (size_t)bc * (H_ * W_));

    __shared__ __align__(16) float sp[NROW * PSTR];          // sigmoid(logits), 20.96 KB
    __shared__ __align__(16) unsigned char st8[NROW * TSTR]; // targets as bytes, 5.44 KB
    __shared__ float red[4][4];

    const int tid = threadIdx.x;

    // Zero pad columns. Layout: image col gx lives at offset gx+4.
    // Left pad offsets 0..3 (gx=-4..-1), right pad offset 516 (gx=512).
    if (tid < NROW) {
        *(float4*)&sp[tid * PSTR] = make_float4(0.f, 0.f, 0.f, 0.f);
        sp[tid * PSTR + 516] = 0.f;
        *(unsigned int*)&st8[tid * TSTR] = 0u;
        *(unsigned int*)&st8[tid * TSTR + 516] = 0u;  // bytes 516..519
    }

    // Stage 10 rows x 512 cols, float4-coalesced. Row halos outside image -> zeros.
    #pragma unroll
    for (int i = 0; i < 5; ++i) {
        int idx = tid + i * NT;       // 0..1279
        int row = idx >> 7;           // 0..9
        int c4  = idx & 127;
        int gy  = y0 - 1 + row;
        float4 pv = make_float4(0.f, 0.f, 0.f, 0.f);
        unsigned int tw = 0u;
        if ((unsigned)gy < (unsigned)H_) {
            float4 x = lg4[gy * 128 + c4];
            pv.x = __builtin_amdgcn_rcpf(1.f + __expf(-x.x));
            pv.y = __builtin_amdgcn_rcpf(1.f + __expf(-x.y));
            pv.z = __builtin_amdgcn_rcpf(1.f + __expf(-x.z));
            pv.w = __builtin_amdgcn_rcpf(1.f + __expf(-x.w));
            float4 t = tg4[gy * 128 + c4];
            tw  = (t.x > 0.5f) ? 1u : 0u;
            tw |= (t.y > 0.5f) ? (1u << 8) : 0u;
            tw |= (t.z > 0.5f) ? (1u << 16) : 0u;
            tw |= (t.w > 0.5f) ? (1u << 24) : 0u;
        }
        *(float4*)&sp[row * PSTR + 4 + c4 * 4] = pv;
        *(unsigned int*)&st8[row * TSTR + 4 + c4 * 4] = tw;
    }
    __syncthreads();

    // Each thread owns a 16-px horizontal run: image row ry (LDS rows ry..ry+2),
    // cols rx..rx+15. Needs LDS col offsets rx+3 .. rx+20.
    const int ry = tid & 7;
    const int rx = (tid >> 3) << 4;   // 0..496

    // ---------- targets: exact integer SWAR Sobel ----------
    int tbmask = 0, tcmask = 0;
    {
        unsigned int r0w[6], r1w[6], r2w[6], vtb[6], vsb[6];
        const unsigned char* tb0 = &st8[ry * TSTR + rx];
        {
            uint4 q = *(const uint4*)tb0;               uint2 q2 = *(const uint2*)(tb0 + 16);
            r0w[0]=q.x; r0w[1]=q.y; r0w[2]=q.z; r0w[3]=q.w; r0w[4]=q2.x; r0w[5]=q2.y;
        }
        {
            uint4 q = *(const uint4*)(tb0 + TSTR);      uint2 q2 = *(const uint2*)(tb0 + TSTR + 16);
            r1w[0]=q.x; r1w[1]=q.y; r1w[2]=q.z; r1w[3]=q.w; r1w[4]=q2.x; r1w[5]=q2.y;
        }
        {
            uint4 q = *(const uint4*)(tb0 + 2*TSTR);    uint2 q2 = *(const uint2*)(tb0 + 2*TSTR + 16);
            r2w[0]=q.x; r2w[1]=q.y; r2w[2]=q.z; r2w[3]=q.w; r2w[4]=q2.x; r2w[5]=q2.y;
        }
        #pragma unroll
        for (int j = 0; j < 6; ++j) {
            // byte lanes hold values in {0,1}; sums <= 4 so no cross-byte carry
            vtb[j] = r0w[j] + (r1w[j] << 1) + r2w[j];
            vsb[j] = (r2w[j] + 0x01010101u) - r0w[j];   // biased by +1/byte, in {0,1,2}
        }
        #pragma unroll
        for (int k = 0; k < 16; ++k) {
            const int b3 = k + 3, b4 = k + 4, b5 = k + 5;
            int t3 = (int)((vtb[b3 >> 2] >> ((b3 & 3) * 8)) & 0xFFu);
            int t5 = (int)((vtb[b5 >> 2] >> ((b5 & 3) * 8)) & 0xFFu);
            int s3 = (int)((vsb[b3 >> 2] >> ((b3 & 3) * 8)) & 0xFFu);
            int s4 = (int)((vsb[b4 >> 2] >> ((b4 & 3) * 8)) & 0xFFu);
            int s5 = (int)((vsb[b5 >> 2] >> ((b5 & 3) * 8)) & 0xFFu);
            int gxt = t5 - t3;                // exact Sobel-x
            int gyt = s3 + 2 * s4 + s5 - 4;   // exact Sobel-y (bias 4 removed)
            tbmask |= (((gxt | gyt) != 0) ? 1 : 0) << k;
            tcmask |= (int)((r1w[b4 >> 2] >> ((b4 & 3) * 8)) & 1u) << k;
        }
    }

    // ---------- probs: separable Sobel via column sums ----------
    float a1[21], vt[18], vs[18];
    {
        float t0[21];
        const float* p0 = &sp[ry * PSTR + rx];
        #pragma unroll
        for (int j = 0; j < 5; ++j) {
            float4 v = *(const float4*)(p0 + 4 * j);
            t0[4*j] = v.x; t0[4*j+1] = v.y; t0[4*j+2] = v.z; t0[4*j+3] = v.w;
        }
        t0[20] = p0[20];
        #pragma unroll
        for (int j = 0; j < 5; ++j) {
            float4 v = *(const float4*)(p0 + PSTR + 4 * j);
            a1[4*j] = v.x; a1[4*j+1] = v.y; a1[4*j+2] = v.z; a1[4*j+3] = v.w;
        }
        a1[20] = p0[PSTR + 20];
        #pragma unroll
        for (int c = 0; c < 18; ++c) {
            vt[c] = t0[c + 3] + 2.f * a1[c + 3];
            vs[c] = -t0[c + 3];
        }
        #pragma unroll
        for (int j = 0; j < 5; ++j) {
            float4 v = *(const float4*)(p0 + 2 * PSTR + 4 * j);
            t0[4*j] = v.x; t0[4*j+1] = v.y; t0[4*j+2] = v.z; t0[4*j+3] = v.w;
        }
        t0[20] = p0[2 * PSTR + 20];
        #pragma unroll
        for (int c = 0; c < 18; ++c) {
            vt[c] += t0[c + 3];
            vs[c] += t0[c + 3];
        }
    }

    float l_i = 0.f, l_p = 0.f;
    int mcnt = 0;
    #pragma unroll
    for (int k = 0; k < 16; ++k) {
        float gx = vt[k + 2] - vt[k];
        float gy = vs[k] + 2.f * vs[k + 1] + vs[k + 2];
        int pb = (gx * gx + gy * gy > 0.25f) ? 1 : 0;
        mcnt += pb ^ ((tbmask >> k) & 1);
        float p = a1[k + 4];
        l_p += p;
        if ((tcmask >> k) & 1) l_i += p;
    }
    float l_t = (float)__popc(tcmask & 0xFFFF);
    float l_m = (float)mcnt;

    // ---------- reduce: wave shuffle then cross-wave LDS ----------
    #pragma unroll
    for (int off = 32; off > 0; off >>= 1) {
        l_i += __shfl_down(l_i, off, 64);
        l_p += __shfl_down(l_p, off, 64);
        l_t += __shfl_down(l_t, off, 64);
        l_m += __shfl_down(l_m, off, 64);
    }
    int wid = tid >> 6, lane = tid & 63;
    if (lane == 0) { red[wid][0] = l_i; red[wid][1] = l_p; red[wid][2] = l_t; red[wid][3] = l_m; }
    __syncthreads();
    if (tid == 0) {
        float s0 = 0.f, s1 = 0.f, s2 = 0.f, s3 = 0.f;
        #pragma unroll
        for (int w = 0; w < 4; ++w) { s0 += red[w][0]; s1 += red[w][1]; s2 += red[w][2]; s3 += red[w][3]; }
        part[blockIdx.y * gridDim.x + blockIdx.x] = make_float4(s0, s1, s2, s3);
    }
}

__global__ void finalize_kernel(const float4* __restrict__ part,
                                const float* __restrict__ cw,
                                float* __restrict__ out) {
    __shared__ float s_i[NIMG], s_p[NIMG], s_t[NIMG], s_m[4];
    const int tid = threadIdx.x, w = tid >> 6, l = tid & 63;
    float vm = 0.f;
    for (int j = 0; j < 8; ++j) {
        int img = w * 8 + j;                   // wave w reduces images w*8..w*8+7
        float4 v = part[img * 64 + l];         // 64 tile-partials per image, one per lane
        vm += v.w;
        float vi = v.x, vp = v.y, vt = v.z;
        #pragma unroll
        for (int off = 32; off > 0; off >>= 1) {
            vi += __shfl_down(vi, off, 64);
            vp += __shfl_down(vp, off, 64);
            vt += __shfl_down(vt, off, 64);
        }
        if (l == 0) { s_i[img] = vi; s_p[img] = vp; s_t[img] = vt; }
    }
    #pragma unroll
    for (int off = 32; off > 0; off >>= 1) vm += __shfl_down(vm, off, 64);
    if (l == 0) s_m[w] = vm;
    __syncthreads();
    if (tid == 0) {
        float mm = s_m[0] + s_m[1] + s_m[2] + s_m[3];
        float wsum = 0.f, dl = 0.f;
        for (int c = 0; c < C_; ++c) {
            float md = 0.f;
            for (int b = 0; b < B_; ++b) {
                int i2 = b * C_ + c;
                md += (2.f * s_i[i2] + 1.f) / (s_p[i2] + s_t[i2] + 1.f);
            }
            md *= 0.125f;
            dl += cw[c] * (1.f - md);
            wsum += cw[c];
        }
        out[0] = 0.7f * (dl / wsum) + 0.3f * (100.f * mm / NPIXF);
    }
}

extern "C" void kernel_launch(void* const* d_in, const int* in_sizes, int n_in,
                              void* d_out, int out_size, void* d_ws, size_t ws_size,
                              hipStream_t stream) {
    const float* logits  = (const float*)d_in[0];
    const float* targets = (const float*)d_in[1];
    const float* cw      = (const float*)d_in[2];
    float* out = (float*)d_out;
    float4* part = (float4*)d_ws;   // 2048 * float4 = 32 KB

    dim3 grid(H_ / TH, NIMG);       // (64, 32)
    fused_loss_kernel<<<grid, NT, 0, stream>>>(logits, targets, part);
    finalize_kernel<<<1, NT, 0, stream>>>(part, cw, out);
}

// Round 4
// 101.074 us; speedup vs baseline: 1.3677x; 1.0777x over previous
//
#include <hip/hip_runtime.h>

// CombinedLoss = 0.7 * class-weighted Dice + 0.3 * Sobel-boundary BCE
// [B=8,C=4,H=512,W=512] fp32. Binary boundary BCE == 100 * mismatch-rate.
// Register-streaming design: one wave = one full 512-col row strip (8 cols/lane),
// 4 output rows/wave, 5-slot register row window, depth-2 prefetch, shuffle halos.
// No LDS tiles, no mid-kernel barriers.

#define H_ 512
#define W_ 512
#define NIMG 32
#define NPIXF 8388608.0f
#define R_ 4        // output rows per wave
#define NBLK 1024   // 32 img * 128 segs / 4 waves-per-block

__device__ __forceinline__ float sigf(float x) {
    return __builtin_amdgcn_rcpf(1.f + __expf(-x));
}

__launch_bounds__(256, 2)
__global__ void fused_loss_kernel(const float* __restrict__ logits,
                                  const float* __restrict__ targets,
                                  float4* __restrict__ part) {
    const int tid  = threadIdx.x;
    const int wid  = tid >> 6, lane = tid & 63;
    const int bx   = blockIdx.x;
    const int img  = bx >> 5;                  // 32 blocks per image
    const int seg  = ((bx & 31) << 2) | wid;   // 128 segments per image
    const int y0   = seg << 2;

    const float* Lp = logits  + (size_t)img * (H_ * W_) + (lane << 3);
    const float* Tp = targets + (size_t)img * (H_ * W_) + (lane << 3);

    float p[5][8], t[5][8];   // 5-slot row window, 8 cols/lane

    auto loadrow = [&](int gy, int s) {
        if ((unsigned)gy < (unsigned)H_) {
            const float4 va = *(const float4*)(Lp + gy * W_);
            const float4 vb = *(const float4*)(Lp + gy * W_ + 4);
            const float4 vc = *(const float4*)(Tp + gy * W_);
            const float4 vd = *(const float4*)(Tp + gy * W_ + 4);
            p[s][0] = sigf(va.x); p[s][1] = sigf(va.y);
            p[s][2] = sigf(va.z); p[s][3] = sigf(va.w);
            p[s][4] = sigf(vb.x); p[s][5] = sigf(vb.y);
            p[s][6] = sigf(vb.z); p[s][7] = sigf(vb.w);
            t[s][0] = vc.x; t[s][1] = vc.y; t[s][2] = vc.z; t[s][3] = vc.w;
            t[s][4] = vd.x; t[s][5] = vd.y; t[s][6] = vd.z; t[s][7] = vd.w;
        } else {
            #pragma unroll
            for (int k = 0; k < 8; ++k) { p[s][k] = 0.f; t[s][k] = 0.f; }
        }
    };

    loadrow(y0 - 1, 0);
    loadrow(y0,     1);
    loadrow(y0 + 1, 2);
    loadrow(y0 + 2, 3);

    float li = 0.f, lp = 0.f, lt = 0.f;
    int mi = 0;

    #pragma unroll
    for (int i = 0; i < R_; ++i) {
        if (i < 2) loadrow(y0 + 3 + i, (4 + i) % 5);   // depth-2 prefetch
        const int sA = i % 5, sB = (i + 1) % 5, sC = (i + 2) % 5;

        float Tc[8], Sc[8], Tt[8], St[8];
        #pragma unroll
        for (int k = 0; k < 8; ++k) {
            Tc[k] = (p[sA][k] + p[sC][k]) + 2.f * p[sB][k];
            Sc[k] = p[sC][k] - p[sA][k];
            Tt[k] = (t[sA][k] + t[sC][k]) + 2.f * t[sB][k];
            St[k] = t[sC][k] - t[sA][k];
        }
        // horizontal halo from neighbor lanes
        float TL = __shfl_up(Tc[7], 1, 64), TR = __shfl_down(Tc[0], 1, 64);
        float SL = __shfl_up(Sc[7], 1, 64), SR = __shfl_down(Sc[0], 1, 64);
        float UL = __shfl_up(Tt[7], 1, 64), UR = __shfl_down(Tt[0], 1, 64);
        float VL = __shfl_up(St[7], 1, 64), VR = __shfl_down(St[0], 1, 64);
        if (lane == 0)  { TL = 0.f; SL = 0.f; UL = 0.f; VL = 0.f; }
        if (lane == 63) { TR = 0.f; SR = 0.f; UR = 0.f; VR = 0.f; }

        #pragma unroll
        for (int k = 0; k < 8; ++k) {
            const float tl = (k == 0) ? TL : Tc[k - 1];
            const float tr = (k == 7) ? TR : Tc[k + 1];
            const float sl = (k == 0) ? SL : Sc[k - 1];
            const float sr = (k == 7) ? SR : Sc[k + 1];
            const float gx = tr - tl;
            const float gy = (sl + sr) + 2.f * Sc[k];
            const int pb = (gx * gx + gy * gy) > 0.25f;

            const float ul = (k == 0) ? UL : Tt[k - 1];
            const float ur = (k == 7) ? UR : Tt[k + 1];
            const float vl = (k == 0) ? VL : St[k - 1];
            const float vr = (k == 7) ? VR : St[k + 1];
            const float hx = ur - ul;
            const float hy = (vl + vr) + 2.f * St[k];
            const int tb = (hx * hx + hy * hy) > 0.25f;   // exact: integer-valued

            mi += pb ^ tb;
            const float pv = p[sB][k], tv = t[sB][k];
            lp += pv; lt += tv; li += pv * tv;
        }
    }
    float lm = (float)mi;

    #pragma unroll
    for (int off = 32; off > 0; off >>= 1) {
        li += __shfl_down(li, off, 64);
        lp += __shfl_down(lp, off, 64);
        lt += __shfl_down(lt, off, 64);
        lm += __shfl_down(lm, off, 64);
    }
    __shared__ float red[4][4];
    if (lane == 0) { red[wid][0] = li; red[wid][1] = lp; red[wid][2] = lt; red[wid][3] = lm; }
    __syncthreads();
    if (tid == 0) {
        float a = 0.f, b = 0.f, c = 0.f, d = 0.f;
        #pragma unroll
        for (int w = 0; w < 4; ++w) {
            a += red[w][0]; b += red[w][1]; c += red[w][2]; d += red[w][3];
        }
        part[bx] = make_float4(a, b, c, d);
    }
}

__global__ void finalize_kernel(const float4* __restrict__ part,
                                const float* __restrict__ cw,
                                float* __restrict__ out) {
    __shared__ float s_i[NIMG], s_p[NIMG], s_t[NIMG], s_m[NIMG];
    const int tid = threadIdx.x;           // 1024 threads, one per block-partial
    float4 v = part[tid];
    float vi = v.x, vp = v.y, vt = v.z, vm = v.w;
    #pragma unroll
    for (int off = 16; off > 0; off >>= 1) {   // 32 partials per image, segmented
        vi += __shfl_down(vi, off, 32);
        vp += __shfl_down(vp, off, 32);
        vt += __shfl_down(vt, off, 32);
        vm += __shfl_down(vm, off, 32);
    }
    if ((tid & 31) == 0) {
        const int img = tid >> 5;
        s_i[img] = vi; s_p[img] = vp; s_t[img] = vt; s_m[img] = vm;
    }
    __syncthreads();
    if (tid == 0) {
        float mm = 0.f;
        for (int i = 0; i < NIMG; ++i) mm += s_m[i];
        float wsum = 0.f, dl = 0.f;
        for (int c = 0; c < 4; ++c) {
            float md = 0.f;
            for (int b = 0; b < 8; ++b) {
                const int id = b * 4 + c;
                md += (2.f * s_i[id] + 1.f) / (s_p[id] + s_t[id] + 1.f);
            }
            md *= 0.125f;
            dl += cw[c] * (1.f - md);
            wsum += cw[c];
        }
        out[0] = 0.7f * (dl / wsum) + 0.3f * (100.f * mm / NPIXF);
    }
}

extern "C" void kernel_launch(void* const* d_in, const int* in_sizes, int n_in,
                              void* d_out, int out_size, void* d_ws, size_t ws_size,
                              hipStream_t stream) {
    const float* logits  = (const float*)d_in[0];
    const float* targets = (const float*)d_in[1];
    const float* cw      = (const float*)d_in[2];
    float* out = (float*)d_out;
    float4* part = (float4*)d_ws;   // NBLK * 16 B = 16 KB

    fused_loss_kernel<<<NBLK, 256, 0, stream>>>(logits, targets, part);
    finalize_kernel<<<1, NBLK, 0, stream>>>(part, cw, out);
}